// Round 1
// baseline (1860.628 us; speedup 1.0000x reference)
//
#include <hip/hip_runtime.h>

// EnhancedGNN on MI355X.
// Pipeline: CSR build -> [mm -> gather-agg(+bias,relu) -> BN stats -> BN apply(+res)] x3
//           -> mm(64->2) -> gather-agg -> segment mean pool.
// All fp32 VALU (no fp32 MFMA on CDNA4); BN stats accumulate in fp64.

#define NN 100000
#define NE 1200000
#define NBATCH 64
#define IND 128
#define HID 64
#define EPSF 1e-5f

// ---------------- graph prep ----------------
__global__ void k_count(const int* __restrict__ dst, int* __restrict__ cnt) {
  int e = blockIdx.x * 256 + threadIdx.x;
  if (e < NE) atomicAdd(&cnt[dst[e]], 1);
}

__global__ void k_scan_partial(const int* __restrict__ cnt, int* __restrict__ bsum) {
  __shared__ int red[256];
  int base = blockIdx.x * 1024;
  int s = 0;
  for (int i = threadIdx.x; i < 1024; i += 256) {
    int idx = base + i;
    if (idx < NN) s += cnt[idx];
  }
  red[threadIdx.x] = s;
  __syncthreads();
  for (int off = 128; off > 0; off >>= 1) {
    if (threadIdx.x < off) red[threadIdx.x] += red[threadIdx.x + off];
    __syncthreads();
  }
  if (threadIdx.x == 0) bsum[blockIdx.x] = red[0];
}

__global__ void k_scan_serial(int* __restrict__ bsum, int nb) {
  if (threadIdx.x == 0 && blockIdx.x == 0) {
    int acc = 0;
    for (int i = 0; i < nb; i++) { int v = bsum[i]; bsum[i] = acc; acc += v; }
  }
}

__global__ void k_scan_apply(const int* __restrict__ cnt, const int* __restrict__ bsum,
                             int* __restrict__ row_start, int* __restrict__ cursor) {
  __shared__ int a[256];
  int tid = threadIdx.x;
  int base = blockIdx.x * 1024 + tid * 4;
  int loc[4];
  int tsum = 0;
  for (int j = 0; j < 4; j++) {
    int idx = base + j;
    int v = (idx < NN) ? cnt[idx] : 0;
    loc[j] = tsum;
    tsum += v;
  }
  a[tid] = tsum;
  __syncthreads();
  // Hillis-Steele inclusive scan over thread sums
  for (int off = 1; off < 256; off <<= 1) {
    int v = (tid >= off) ? a[tid - off] : 0;
    __syncthreads();
    a[tid] += v;
    __syncthreads();
  }
  int texcl = a[tid] - tsum + bsum[blockIdx.x];
  for (int j = 0; j < 4; j++) {
    int idx = base + j;
    if (idx < NN) {
      int v = texcl + loc[j];
      row_start[idx] = v;
      cursor[idx] = v;
    }
  }
}

__global__ void k_dinv(const int* __restrict__ cnt, float* __restrict__ dinv) {
  int i = blockIdx.x * 256 + threadIdx.x;
  if (i < NN) dinv[i] = rsqrtf((float)cnt[i] + 1.0f);
}

__global__ void k_fill(const int* __restrict__ src, const int* __restrict__ dst,
                       int* __restrict__ cursor, int* __restrict__ col) {
  int e = blockIdx.x * 256 + threadIdx.x;
  if (e < NE) {
    int d = dst[e];
    int pos = atomicAdd(&cursor[d], 1);
    col[pos] = src[e];
  }
}

// ---------------- dense matmul: X[nrows,K] @ W[K,64] -> T[nrows,64] ----------------
template <int K>
__global__ void k_mm(const float* __restrict__ X, const float* __restrict__ W,
                     float* __restrict__ T, int nrows) {
  __shared__ float Ws[K * 64];
  __shared__ float Xs[16 * K];
  int tid = threadIdx.x;
  for (int i = tid; i < K * 64; i += 256) Ws[i] = W[i];
  int nb = blockIdx.x * 16;
  for (int i = tid; i < 16 * K; i += 256) {
    int r = i / K, c = i % K;
    int row = nb + r;
    Xs[i] = (row < nrows) ? X[(size_t)row * K + c] : 0.f;
  }
  __syncthreads();
  int f = tid & 63;
  int g = tid >> 6;  // 0..3; nodes g, g+4, g+8, g+12
  float acc0 = 0.f, acc1 = 0.f, acc2 = 0.f, acc3 = 0.f;
  for (int k = 0; k < K; k++) {
    float wv = Ws[k * 64 + f];
    acc0 += Xs[(g + 0) * K + k] * wv;
    acc1 += Xs[(g + 4) * K + k] * wv;
    acc2 += Xs[(g + 8) * K + k] * wv;
    acc3 += Xs[(g + 12) * K + k] * wv;
  }
  float accs[4] = {acc0, acc1, acc2, acc3};
  for (int j = 0; j < 4; j++) {
    int row = nb + g + j * 4;
    if (row < nrows) T[(size_t)row * 64 + f] = accs[j];
  }
}

// ---------------- aggregation (HID=64): one wave per node ----------------
__global__ void k_agg64(const float* __restrict__ T, const int* __restrict__ row_start,
                        const int* __restrict__ cnt, const int* __restrict__ col,
                        const float* __restrict__ dinv, const float* __restrict__ bias,
                        float* __restrict__ G, int relu) {
  int lane = threadIdx.x & 63;
  int wv = threadIdx.x >> 6;
  int node = blockIdx.x * 4 + wv;
  if (node >= NN) return;
  int s = row_start[node];
  int c = cnt[node];
  float acc = 0.f;
  for (int i = 0; i < c; i++) {
    int src = col[s + i];
    acc += T[(size_t)src * 64 + lane] * dinv[src];
  }
  float di = dinv[node];
  float v = acc * di + T[(size_t)node * 64 + lane] * di * di + bias[lane];
  if (relu) v = fmaxf(v, 0.f);
  G[(size_t)node * 64 + lane] = v;
}

// ---------------- BN stats: per-feature sum & sumsq -> fp64 accumulators ----------------
__global__ void k_stats(const float* __restrict__ H, double* __restrict__ st) {
  int f = threadIdx.x & 63;
  int g = threadIdx.x >> 6;
  float s1 = 0.f, s2 = 0.f;
  for (int r = blockIdx.x * 4 + g; r < NN; r += gridDim.x * 4) {
    float v = H[(size_t)r * 64 + f];
    s1 += v;
    s2 += v * v;
  }
  __shared__ float a[256], b[256];
  a[threadIdx.x] = s1;
  b[threadIdx.x] = s2;
  __syncthreads();
  if (threadIdx.x < 64) {
    float t1 = a[f] + a[f + 64] + a[f + 128] + a[f + 192];
    float t2 = b[f] + b[f + 64] + b[f + 128] + b[f + 192];
    unsafeAtomicAdd(&st[f], (double)t1);
    unsafeAtomicAdd(&st[64 + f], (double)t2);
  }
}

__global__ void k_bnscale(const double* __restrict__ st, const float* __restrict__ gamma,
                          const float* __restrict__ beta, float* __restrict__ sc) {
  int f = threadIdx.x;
  if (f < 64) {
    double m = st[f] / (double)NN;
    double var = st[64 + f] / (double)NN - m * m;
    float scale = gamma[f] * rsqrtf((float)var + EPSF);
    sc[f] = scale;
    sc[64 + f] = beta[f] - (float)m * scale;
  }
}

// ---------------- BN apply (+ optional residual), float4 over [N,64] ----------------
__global__ void k_bnapply(const float* __restrict__ G, const float* __restrict__ sc,
                          const float* __restrict__ res, float* __restrict__ Hout) {
  int i = blockIdx.x * 256 + threadIdx.x;  // float4 index; N*64/4 = N*16
  if (i >= NN * 16) return;
  float4 v = ((const float4*)G)[i];
  int q = i & 15;  // float4 within 64-float row
  float4 s = ((const float4*)sc)[q];
  float4 sh = ((const float4*)(sc + 64))[q];
  float4 o;
  o.x = v.x * s.x + sh.x;
  o.y = v.y * s.y + sh.y;
  o.z = v.z * s.z + sh.z;
  o.w = v.w * s.w + sh.w;
  if (res != nullptr) {
    float4 r = ((const float4*)res)[i];
    o.x += r.x; o.y += r.y; o.z += r.z; o.w += r.w;
  }
  ((float4*)Hout)[i] = o;
}

// ---------------- output matmul: H[N,64] @ Wout[64,2] -> T2[N,2] ----------------
__global__ void k_mmout(const float* __restrict__ H, const float* __restrict__ W,
                        float* __restrict__ T2) {
  __shared__ float Hs[64 * 65];  // +1 pad to break 64-stride bank aliasing
  __shared__ float Ws[128];
  int tid = threadIdx.x;
  if (tid < 128) Ws[tid] = W[tid];
  int nb = blockIdx.x * 64;
  for (int i = tid; i < 64 * 64; i += 256) {
    int r = i >> 6, c = i & 63;
    int row = nb + r;
    Hs[r * 65 + c] = (row < NN) ? H[(size_t)row * 64 + c] : 0.f;
  }
  __syncthreads();
  if (tid < 128) {
    int nl = tid >> 1, f = tid & 1;
    int row = nb + nl;
    if (row < NN) {
      float acc = 0.f;
      for (int k = 0; k < 64; k++) acc += Hs[nl * 65 + k] * Ws[k * 2 + f];
      T2[(size_t)row * 2 + f] = acc;
    }
  }
}

// ---------------- final aggregation (dim 2) ----------------
__global__ void k_agg2(const float* __restrict__ T2, const int* __restrict__ row_start,
                       const int* __restrict__ cnt, const int* __restrict__ col,
                       const float* __restrict__ dinv, const float* __restrict__ bias,
                       float* __restrict__ G2) {
  int idx = blockIdx.x * 256 + threadIdx.x;
  if (idx >= NN * 2) return;
  int node = idx >> 1, f = idx & 1;
  int s = row_start[node];
  int c = cnt[node];
  float acc = 0.f;
  for (int i = 0; i < c; i++) {
    int src = col[s + i];
    acc += T2[(size_t)src * 2 + f] * dinv[src];
  }
  float di = dinv[node];
  G2[idx] = acc * di + T2[idx] * di * di + bias[f];
}

// ---------------- segment mean pool ----------------
__global__ void k_pool(const float* __restrict__ G2, const int* __restrict__ batch,
                       float* __restrict__ pool, int* __restrict__ pcnt) {
  __shared__ float pl[128];
  __shared__ int pc[64];
  int tid = threadIdx.x;
  if (tid < 128) pl[tid] = 0.f;
  if (tid < 64) pc[tid] = 0;
  __syncthreads();
  int node = blockIdx.x * 128 + (tid >> 1);
  int f = tid & 1;
  if (node < NN) {
    int b = batch[node];
    atomicAdd(&pl[b * 2 + f], G2[(size_t)node * 2 + f]);
    if (f == 0) atomicAdd(&pc[b], 1);
  }
  __syncthreads();
  if (tid < 128 && pl[tid] != 0.f) unsafeAtomicAdd(&pool[tid], pl[tid]);
  if (tid < 64 && pc[tid] != 0) atomicAdd(&pcnt[tid], pc[tid]);
}

__global__ void k_div(const float* __restrict__ pool, const int* __restrict__ pcnt,
                      float* __restrict__ out) {
  int i = threadIdx.x;
  if (i < 128) {
    int c = pcnt[i >> 1];
    out[i] = pool[i] / (float)(c > 0 ? c : 1);
  }
}

extern "C" void kernel_launch(void* const* d_in, const int* in_sizes, int n_in,
                              void* d_out, int out_size, void* d_ws, size_t ws_size,
                              hipStream_t stream) {
  (void)in_sizes; (void)n_in; (void)out_size; (void)ws_size;
  const float* x     = (const float*)d_in[0];
  const float* W_in  = (const float*)d_in[1];
  const float* b_in  = (const float*)d_in[2];
  const float* W_h   = (const float*)d_in[3];
  const float* b_h   = (const float*)d_in[4];
  const float* W_out = (const float*)d_in[5];
  const float* b_out = (const float*)d_in[6];
  const float* gamma = (const float*)d_in[7];
  const float* beta  = (const float*)d_in[8];
  const int*   ei    = (const int*)d_in[9];
  const int*   batch = (const int*)d_in[10];
  const int* src = ei;
  const int* dst = ei + NE;
  float* out = (float*)d_out;

  char* w = (char*)d_ws;
  size_t off = 0;
  auto alloc = [&](size_t bytes) -> void* {
    void* p = (void*)(w + off);
    off += (bytes + 511) & ~(size_t)511;
    return p;
  };
  int*    deg   = (int*)alloc((size_t)NN * 4);
  int*    rowp  = (int*)alloc((size_t)NN * 4);
  int*    cur   = (int*)alloc((size_t)NN * 4);
  int*    col   = (int*)alloc((size_t)NE * 4);
  float*  dinv  = (float*)alloc((size_t)NN * 4);
  int*    bsum  = (int*)alloc(512);
  char*   zzone = (char*)alloc(3840);  // stats: 3*128 doubles, pool: 128 f, pcnt: 64 i
  double* stats = (double*)zzone;
  float*  pool  = (float*)(zzone + 3072);
  int*    pcnt  = (int*)(zzone + 3072 + 512);
  float*  bnsc  = (float*)alloc(512);
  float*  buf0  = (float*)alloc((size_t)NN * HID * 4);
  float*  buf1  = (float*)alloc((size_t)NN * HID * 4);
  float*  buf2  = (float*)alloc((size_t)NN * HID * 4);
  float*  T2    = (float*)alloc((size_t)NN * 2 * 4);
  float*  G2    = (float*)alloc((size_t)NN * 2 * 4);
  // total ws use ~85 MB

  hipMemsetAsync(deg, 0, (size_t)NN * 4, stream);
  hipMemsetAsync(zzone, 0, 3840, stream);

  // graph prep
  k_count<<<(NE + 255) / 256, 256, 0, stream>>>(dst, deg);
  k_scan_partial<<<98, 256, 0, stream>>>(deg, bsum);
  k_scan_serial<<<1, 64, 0, stream>>>(bsum, 98);
  k_scan_apply<<<98, 256, 0, stream>>>(deg, bsum, rowp, cur);
  k_dinv<<<(NN + 255) / 256, 256, 0, stream>>>(deg, dinv);
  k_fill<<<(NE + 255) / 256, 256, 0, stream>>>(src, dst, cur, col);

  // layer 1: x(128) -> buf2(64)
  k_mm<IND><<<(NN + 15) / 16, 256, 0, stream>>>(x, W_in, buf0, NN);
  k_agg64<<<(NN + 3) / 4, 256, 0, stream>>>(buf0, rowp, deg, col, dinv, b_in, buf1, 1);
  k_stats<<<512, 256, 0, stream>>>(buf1, stats);
  k_bnscale<<<1, 64, 0, stream>>>(stats, gamma, beta, bnsc);
  k_bnapply<<<6250, 256, 0, stream>>>(buf1, bnsc, nullptr, buf2);

  // layer 2: buf2 -> buf0 (res buf2)
  k_mm<HID><<<(NN + 15) / 16, 256, 0, stream>>>(buf2, W_h, buf0, NN);
  k_agg64<<<(NN + 3) / 4, 256, 0, stream>>>(buf0, rowp, deg, col, dinv, b_h, buf1, 1);
  k_stats<<<512, 256, 0, stream>>>(buf1, stats + 128);
  k_bnscale<<<1, 64, 0, stream>>>(stats + 128, gamma + 64, beta + 64, bnsc);
  k_bnapply<<<6250, 256, 0, stream>>>(buf1, bnsc, buf2, buf0);

  // layer 3: buf0 -> buf1 (res buf0)
  k_mm<HID><<<(NN + 15) / 16, 256, 0, stream>>>(buf0, W_h + HID * HID, buf1, NN);
  k_agg64<<<(NN + 3) / 4, 256, 0, stream>>>(buf1, rowp, deg, col, dinv, b_h + HID, buf2, 1);
  k_stats<<<512, 256, 0, stream>>>(buf2, stats + 256);
  k_bnscale<<<1, 64, 0, stream>>>(stats + 256, gamma + 128, beta + 128, bnsc);
  k_bnapply<<<6250, 256, 0, stream>>>(buf2, bnsc, buf0, buf1);

  // output layer: buf1 -> out
  k_mmout<<<(NN + 63) / 64, 256, 0, stream>>>(buf1, W_out, T2);
  k_agg2<<<(2 * NN + 255) / 256, 256, 0, stream>>>(T2, rowp, deg, col, dinv, b_out, G2);
  k_pool<<<(NN + 127) / 128, 256, 0, stream>>>(G2, batch, pool, pcnt);
  k_div<<<1, 128, 0, stream>>>(pool, pcnt, out);
}

// Round 2
// 805.476 us; speedup vs baseline: 2.3100x; 2.3100x over previous
//
#include <hip/hip_runtime.h>

// EnhancedGNN on MI355X.
// Pipeline: CSR build -> [mm -> gather-agg(+bias,relu) -> BN stats -> BN apply(+res)] x3
//           -> mm(64->2) -> gather-agg -> segment mean pool.
// R1: mm rewritten as weight-stationary-in-VGPR + wave-uniform row broadcast
//     (old LDS version was 5 ds_read per 8 FMA, latency-bound at ~515us/dispatch).
//     agg64 rewritten with float4 gathers, 4 edges in flight, shfl_xor reduce.

#define NN 100000
#define NE 1200000
#define NBATCH 64
#define IND 128
#define HID 64
#define EPSF 1e-5f

// ---------------- graph prep ----------------
__global__ void k_count(const int* __restrict__ dst, int* __restrict__ cnt) {
  int e = blockIdx.x * 256 + threadIdx.x;
  if (e < NE) atomicAdd(&cnt[dst[e]], 1);
}

__global__ void k_scan_partial(const int* __restrict__ cnt, int* __restrict__ bsum) {
  __shared__ int red[256];
  int base = blockIdx.x * 1024;
  int s = 0;
  for (int i = threadIdx.x; i < 1024; i += 256) {
    int idx = base + i;
    if (idx < NN) s += cnt[idx];
  }
  red[threadIdx.x] = s;
  __syncthreads();
  for (int off = 128; off > 0; off >>= 1) {
    if (threadIdx.x < off) red[threadIdx.x] += red[threadIdx.x + off];
    __syncthreads();
  }
  if (threadIdx.x == 0) bsum[blockIdx.x] = red[0];
}

__global__ void k_scan_serial(int* __restrict__ bsum, int nb) {
  if (threadIdx.x == 0 && blockIdx.x == 0) {
    int acc = 0;
    for (int i = 0; i < nb; i++) { int v = bsum[i]; bsum[i] = acc; acc += v; }
  }
}

__global__ void k_scan_apply(const int* __restrict__ cnt, const int* __restrict__ bsum,
                             int* __restrict__ row_start, int* __restrict__ cursor) {
  __shared__ int a[256];
  int tid = threadIdx.x;
  int base = blockIdx.x * 1024 + tid * 4;
  int loc[4];
  int tsum = 0;
  for (int j = 0; j < 4; j++) {
    int idx = base + j;
    int v = (idx < NN) ? cnt[idx] : 0;
    loc[j] = tsum;
    tsum += v;
  }
  a[tid] = tsum;
  __syncthreads();
  for (int off = 1; off < 256; off <<= 1) {
    int v = (tid >= off) ? a[tid - off] : 0;
    __syncthreads();
    a[tid] += v;
    __syncthreads();
  }
  int texcl = a[tid] - tsum + bsum[blockIdx.x];
  for (int j = 0; j < 4; j++) {
    int idx = base + j;
    if (idx < NN) {
      int v = texcl + loc[j];
      row_start[idx] = v;
      cursor[idx] = v;
    }
  }
}

__global__ void k_dinv(const int* __restrict__ cnt, float* __restrict__ dinv) {
  int i = blockIdx.x * 256 + threadIdx.x;
  if (i < NN) dinv[i] = rsqrtf((float)cnt[i] + 1.0f);
}

__global__ void k_fill(const int* __restrict__ src, const int* __restrict__ dst,
                       int* __restrict__ cursor, int* __restrict__ col) {
  int e = blockIdx.x * 256 + threadIdx.x;
  if (e < NE) {
    int d = dst[e];
    int pos = atomicAdd(&cursor[d], 1);
    col[pos] = src[e];
  }
}

// ---------------- dense matmul: X[nrows,K] @ W[K,64] -> T[nrows,64] ----------------
// Weight-stationary: lane f holds W[:,f] in VGPRs. Each wave owns ROWS rows.
// X rows read as wave-uniform float4 loads (readfirstlane'd base -> scalar path).
template <int K, int ROWS>
__global__ void k_mm2(const float* __restrict__ X, const float* __restrict__ W,
                      float* __restrict__ T, int nrows) {
  int lane = threadIdx.x & 63;
  int wave = threadIdx.x >> 6;
  float wc[K];
#pragma unroll
  for (int k = 0; k < K; k++) wc[k] = W[k * 64 + lane];  // coalesced 256B per instr

  int row0 = __builtin_amdgcn_readfirstlane((blockIdx.x * 4 + wave) * ROWS);
  if (row0 >= nrows) return;

#pragma unroll
  for (int r = 0; r < ROWS; r += 2) {
    int rowA = row0 + r;
    int rowB = row0 + r + 1;
    int rA = rowA < nrows ? rowA : nrows - 1;  // clamp loads, guard stores
    int rB = rowB < nrows ? rowB : nrows - 1;
    const float4* xa = (const float4*)(X + (size_t)rA * K);
    const float4* xb = (const float4*)(X + (size_t)rB * K);
    float accA = 0.f, accB = 0.f;
#pragma unroll
    for (int q = 0; q < K / 4; q++) {
      float4 a = xa[q];
      float4 b = xb[q];
      accA += a.x * wc[4 * q] + a.y * wc[4 * q + 1] + a.z * wc[4 * q + 2] + a.w * wc[4 * q + 3];
      accB += b.x * wc[4 * q] + b.y * wc[4 * q + 1] + b.z * wc[4 * q + 2] + b.w * wc[4 * q + 3];
    }
    if (rowA < nrows) T[(size_t)rowA * 64 + lane] = accA;
    if (rowB < nrows) T[(size_t)rowB * 64 + lane] = accB;
  }
}

// ---------------- aggregation (HID=64): one wave per node, 4 edges in flight ----------------
__global__ void k_agg64(const float* __restrict__ T, const int* __restrict__ row_start,
                        const int* __restrict__ cnt, const int* __restrict__ col,
                        const float* __restrict__ dinv, const float* __restrict__ bias,
                        float* __restrict__ G, int relu) {
  int lane = threadIdx.x & 63;
  int wv = threadIdx.x >> 6;
  int node = blockIdx.x * 4 + wv;
  if (node >= NN) return;
  int grp = lane >> 4;  // which of 4 concurrent edges
  int q = lane & 15;    // float4 slot: features 4q..4q+3
  int s = row_start[node];
  int c = cnt[node];
  float4 acc = {0.f, 0.f, 0.f, 0.f};
  for (int i = 0; i < c; i += 4) {
    int j = i + grp;
    if (j < c) {
      int src = col[s + j];
      float dv = dinv[src];
      float4 t = ((const float4*)(T + (size_t)src * 64))[q];
      acc.x += t.x * dv;
      acc.y += t.y * dv;
      acc.z += t.z * dv;
      acc.w += t.w * dv;
    }
  }
  // reduce over the 4 edge-groups (lanes differing in bits 4,5)
  acc.x += __shfl_xor(acc.x, 16, 64);
  acc.y += __shfl_xor(acc.y, 16, 64);
  acc.z += __shfl_xor(acc.z, 16, 64);
  acc.w += __shfl_xor(acc.w, 16, 64);
  acc.x += __shfl_xor(acc.x, 32, 64);
  acc.y += __shfl_xor(acc.y, 32, 64);
  acc.z += __shfl_xor(acc.z, 32, 64);
  acc.w += __shfl_xor(acc.w, 32, 64);
  if (grp == 0) {
    float di = dinv[node];
    float dd = di * di;
    float4 ts = ((const float4*)(T + (size_t)node * 64))[q];
    float4 bs = ((const float4*)bias)[q];
    float4 o;
    o.x = acc.x * di + ts.x * dd + bs.x;
    o.y = acc.y * di + ts.y * dd + bs.y;
    o.z = acc.z * di + ts.z * dd + bs.z;
    o.w = acc.w * di + ts.w * dd + bs.w;
    if (relu) {
      o.x = fmaxf(o.x, 0.f);
      o.y = fmaxf(o.y, 0.f);
      o.z = fmaxf(o.z, 0.f);
      o.w = fmaxf(o.w, 0.f);
    }
    ((float4*)(G + (size_t)node * 64))[q] = o;
  }
}

// ---------------- BN stats: per-feature sum & sumsq -> fp64 accumulators ----------------
__global__ void k_stats(const float* __restrict__ H, double* __restrict__ st) {
  int f = threadIdx.x & 63;
  int g = threadIdx.x >> 6;
  float s1 = 0.f, s2 = 0.f;
  for (int r = blockIdx.x * 4 + g; r < NN; r += gridDim.x * 4) {
    float v = H[(size_t)r * 64 + f];
    s1 += v;
    s2 += v * v;
  }
  __shared__ float a[256], b[256];
  a[threadIdx.x] = s1;
  b[threadIdx.x] = s2;
  __syncthreads();
  if (threadIdx.x < 64) {
    float t1 = a[f] + a[f + 64] + a[f + 128] + a[f + 192];
    float t2 = b[f] + b[f + 64] + b[f + 128] + b[f + 192];
    unsafeAtomicAdd(&st[f], (double)t1);
    unsafeAtomicAdd(&st[64 + f], (double)t2);
  }
}

__global__ void k_bnscale(const double* __restrict__ st, const float* __restrict__ gamma,
                          const float* __restrict__ beta, float* __restrict__ sc) {
  int f = threadIdx.x;
  if (f < 64) {
    double m = st[f] / (double)NN;
    double var = st[64 + f] / (double)NN - m * m;
    float scale = gamma[f] * rsqrtf((float)var + EPSF);
    sc[f] = scale;
    sc[64 + f] = beta[f] - (float)m * scale;
  }
}

// ---------------- BN apply (+ optional residual), float4 over [N,64] ----------------
__global__ void k_bnapply(const float* __restrict__ G, const float* __restrict__ sc,
                          const float* __restrict__ res, float* __restrict__ Hout) {
  int i = blockIdx.x * 256 + threadIdx.x;  // float4 index; N*64/4 = N*16
  if (i >= NN * 16) return;
  float4 v = ((const float4*)G)[i];
  int q = i & 15;
  float4 s = ((const float4*)sc)[q];
  float4 sh = ((const float4*)(sc + 64))[q];
  float4 o;
  o.x = v.x * s.x + sh.x;
  o.y = v.y * s.y + sh.y;
  o.z = v.z * s.z + sh.z;
  o.w = v.w * s.w + sh.w;
  if (res != nullptr) {
    float4 r = ((const float4*)res)[i];
    o.x += r.x; o.y += r.y; o.z += r.z; o.w += r.w;
  }
  ((float4*)Hout)[i] = o;
}

// ---------------- output matmul: H[N,64] @ Wout[64,2] -> T2[N,2] ----------------
__global__ void k_mmout(const float* __restrict__ H, const float* __restrict__ W,
                        float* __restrict__ T2) {
  __shared__ float Hs[64 * 65];
  __shared__ float Ws[128];
  int tid = threadIdx.x;
  if (tid < 128) Ws[tid] = W[tid];
  int nb = blockIdx.x * 64;
  for (int i = tid; i < 64 * 64; i += 256) {
    int r = i >> 6, c = i & 63;
    int row = nb + r;
    Hs[r * 65 + c] = (row < NN) ? H[(size_t)row * 64 + c] : 0.f;
  }
  __syncthreads();
  if (tid < 128) {
    int nl = tid >> 1, f = tid & 1;
    int row = nb + nl;
    if (row < NN) {
      float acc = 0.f;
      for (int k = 0; k < 64; k++) acc += Hs[nl * 65 + k] * Ws[k * 2 + f];
      T2[(size_t)row * 2 + f] = acc;
    }
  }
}

// ---------------- final aggregation (dim 2) ----------------
__global__ void k_agg2(const float* __restrict__ T2, const int* __restrict__ row_start,
                       const int* __restrict__ cnt, const int* __restrict__ col,
                       const float* __restrict__ dinv, const float* __restrict__ bias,
                       float* __restrict__ G2) {
  int idx = blockIdx.x * 256 + threadIdx.x;
  if (idx >= NN * 2) return;
  int node = idx >> 1, f = idx & 1;
  int s = row_start[node];
  int c = cnt[node];
  float acc = 0.f;
  for (int i = 0; i < c; i++) {
    int src = col[s + i];
    acc += T2[(size_t)src * 2 + f] * dinv[src];
  }
  float di = dinv[node];
  G2[idx] = acc * di + T2[idx] * di * di + bias[f];
}

// ---------------- segment mean pool ----------------
__global__ void k_pool(const float* __restrict__ G2, const int* __restrict__ batch,
                       float* __restrict__ pool, int* __restrict__ pcnt) {
  __shared__ float pl[128];
  __shared__ int pc[64];
  int tid = threadIdx.x;
  if (tid < 128) pl[tid] = 0.f;
  if (tid < 64) pc[tid] = 0;
  __syncthreads();
  int node = blockIdx.x * 128 + (tid >> 1);
  int f = tid & 1;
  if (node < NN) {
    int b = batch[node];
    atomicAdd(&pl[b * 2 + f], G2[(size_t)node * 2 + f]);
    if (f == 0) atomicAdd(&pc[b], 1);
  }
  __syncthreads();
  if (tid < 128 && pl[tid] != 0.f) unsafeAtomicAdd(&pool[tid], pl[tid]);
  if (tid < 64 && pc[tid] != 0) atomicAdd(&pcnt[tid], pc[tid]);
}

__global__ void k_div(const float* __restrict__ pool, const int* __restrict__ pcnt,
                      float* __restrict__ out) {
  int i = threadIdx.x;
  if (i < 128) {
    int c = pcnt[i >> 1];
    out[i] = pool[i] / (float)(c > 0 ? c : 1);
  }
}

extern "C" void kernel_launch(void* const* d_in, const int* in_sizes, int n_in,
                              void* d_out, int out_size, void* d_ws, size_t ws_size,
                              hipStream_t stream) {
  (void)in_sizes; (void)n_in; (void)out_size; (void)ws_size;
  const float* x     = (const float*)d_in[0];
  const float* W_in  = (const float*)d_in[1];
  const float* b_in  = (const float*)d_in[2];
  const float* W_h   = (const float*)d_in[3];
  const float* b_h   = (const float*)d_in[4];
  const float* W_out = (const float*)d_in[5];
  const float* b_out = (const float*)d_in[6];
  const float* gamma = (const float*)d_in[7];
  const float* beta  = (const float*)d_in[8];
  const int*   ei    = (const int*)d_in[9];
  const int*   batch = (const int*)d_in[10];
  const int* src = ei;
  const int* dst = ei + NE;
  float* out = (float*)d_out;

  char* w = (char*)d_ws;
  size_t off = 0;
  auto alloc = [&](size_t bytes) -> void* {
    void* p = (void*)(w + off);
    off += (bytes + 511) & ~(size_t)511;
    return p;
  };
  int*    deg   = (int*)alloc((size_t)NN * 4);
  int*    rowp  = (int*)alloc((size_t)NN * 4);
  int*    cur   = (int*)alloc((size_t)NN * 4);
  int*    col   = (int*)alloc((size_t)NE * 4);
  float*  dinv  = (float*)alloc((size_t)NN * 4);
  int*    bsum  = (int*)alloc(512);
  char*   zzone = (char*)alloc(3840);
  double* stats = (double*)zzone;
  float*  pool  = (float*)(zzone + 3072);
  int*    pcnt  = (int*)(zzone + 3072 + 512);
  float*  bnsc  = (float*)alloc(512);
  float*  buf0  = (float*)alloc((size_t)NN * HID * 4);
  float*  buf1  = (float*)alloc((size_t)NN * HID * 4);
  float*  buf2  = (float*)alloc((size_t)NN * HID * 4);
  float*  T2    = (float*)alloc((size_t)NN * 2 * 4);
  float*  G2    = (float*)alloc((size_t)NN * 2 * 4);

  hipMemsetAsync(deg, 0, (size_t)NN * 4, stream);
  hipMemsetAsync(zzone, 0, 3840, stream);

  // graph prep
  k_count<<<(NE + 255) / 256, 256, 0, stream>>>(dst, deg);
  k_scan_partial<<<98, 256, 0, stream>>>(deg, bsum);
  k_scan_serial<<<1, 64, 0, stream>>>(bsum, 98);
  k_scan_apply<<<98, 256, 0, stream>>>(deg, bsum, rowp, cur);
  k_dinv<<<(NN + 255) / 256, 256, 0, stream>>>(deg, dinv);
  k_fill<<<(NE + 255) / 256, 256, 0, stream>>>(src, dst, cur, col);

  const int MMROWS = 16;
  const int mmgrid = (NN + 4 * MMROWS - 1) / (4 * MMROWS);  // 1563

  // layer 1: x(128) -> buf2(64)
  k_mm2<IND, MMROWS><<<mmgrid, 256, 0, stream>>>(x, W_in, buf0, NN);
  k_agg64<<<(NN + 3) / 4, 256, 0, stream>>>(buf0, rowp, deg, col, dinv, b_in, buf1, 1);
  k_stats<<<512, 256, 0, stream>>>(buf1, stats);
  k_bnscale<<<1, 64, 0, stream>>>(stats, gamma, beta, bnsc);
  k_bnapply<<<6250, 256, 0, stream>>>(buf1, bnsc, nullptr, buf2);

  // layer 2: buf2 -> buf0 (res buf2)
  k_mm2<HID, MMROWS><<<mmgrid, 256, 0, stream>>>(buf2, W_h, buf0, NN);
  k_agg64<<<(NN + 3) / 4, 256, 0, stream>>>(buf0, rowp, deg, col, dinv, b_h, buf1, 1);
  k_stats<<<512, 256, 0, stream>>>(buf1, stats + 128);
  k_bnscale<<<1, 64, 0, stream>>>(stats + 128, gamma + 64, beta + 64, bnsc);
  k_bnapply<<<6250, 256, 0, stream>>>(buf1, bnsc, buf2, buf0);

  // layer 3: buf0 -> buf1 (res buf0)
  k_mm2<HID, MMROWS><<<mmgrid, 256, 0, stream>>>(buf0, W_h + HID * HID, buf1, NN);
  k_agg64<<<(NN + 3) / 4, 256, 0, stream>>>(buf1, rowp, deg, col, dinv, b_h + HID, buf2, 1);
  k_stats<<<512, 256, 0, stream>>>(buf2, stats + 256);
  k_bnscale<<<1, 64, 0, stream>>>(stats + 256, gamma + 128, beta + 128, bnsc);
  k_bnapply<<<6250, 256, 0, stream>>>(buf2, bnsc, buf0, buf1);

  // output layer: buf1 -> out
  k_mmout<<<(NN + 63) / 64, 256, 0, stream>>>(buf1, W_out, T2);
  k_agg2<<<(2 * NN + 255) / 256, 256, 0, stream>>>(T2, rowp, deg, col, dinv, b_out, G2);
  k_pool<<<(NN + 127) / 128, 256, 0, stream>>>(G2, batch, pool, pcnt);
  k_div<<<1, 128, 0, stream>>>(pool, pcnt, out);
}

// Round 3
// 732.834 us; speedup vs baseline: 2.5389x; 1.0991x over previous
//
#include <hip/hip_runtime.h>

// EnhancedGNN on MI355X.
// Pipeline: CSR build -> [mm -> gather-agg(+bias,relu) -> BN stats -> BN apply(+res)] x3
//           -> mm(64->2) -> gather-agg -> segment mean pool.
// R2: mm rewritten lane=row: X staged to LDS transposed (xs[k][row], pad 257),
//     one conflict-free ds_read_b32 per 64 FMAs; W is wave-uniform -> s_load path.
//     (R1's lane=feature version had wave-uniform X = 16 useful B/instr, 170us.)

#define NN 100000
#define NE 1200000
#define NBATCH 64
#define IND 128
#define HID 64
#define EPSF 1e-5f

// ---------------- graph prep ----------------
__global__ void k_count(const int* __restrict__ dst, int* __restrict__ cnt) {
  int e = blockIdx.x * 256 + threadIdx.x;
  if (e < NE) atomicAdd(&cnt[dst[e]], 1);
}

__global__ void k_scan_partial(const int* __restrict__ cnt, int* __restrict__ bsum) {
  __shared__ int red[256];
  int base = blockIdx.x * 1024;
  int s = 0;
  for (int i = threadIdx.x; i < 1024; i += 256) {
    int idx = base + i;
    if (idx < NN) s += cnt[idx];
  }
  red[threadIdx.x] = s;
  __syncthreads();
  for (int off = 128; off > 0; off >>= 1) {
    if (threadIdx.x < off) red[threadIdx.x] += red[threadIdx.x + off];
    __syncthreads();
  }
  if (threadIdx.x == 0) bsum[blockIdx.x] = red[0];
}

__global__ void k_scan_serial(int* __restrict__ bsum, int nb) {
  if (threadIdx.x == 0 && blockIdx.x == 0) {
    int acc = 0;
    for (int i = 0; i < nb; i++) { int v = bsum[i]; bsum[i] = acc; acc += v; }
  }
}

__global__ void k_scan_apply(const int* __restrict__ cnt, const int* __restrict__ bsum,
                             int* __restrict__ row_start, int* __restrict__ cursor) {
  __shared__ int a[256];
  int tid = threadIdx.x;
  int base = blockIdx.x * 1024 + tid * 4;
  int loc[4];
  int tsum = 0;
  for (int j = 0; j < 4; j++) {
    int idx = base + j;
    int v = (idx < NN) ? cnt[idx] : 0;
    loc[j] = tsum;
    tsum += v;
  }
  a[tid] = tsum;
  __syncthreads();
  for (int off = 1; off < 256; off <<= 1) {
    int v = (tid >= off) ? a[tid - off] : 0;
    __syncthreads();
    a[tid] += v;
    __syncthreads();
  }
  int texcl = a[tid] - tsum + bsum[blockIdx.x];
  for (int j = 0; j < 4; j++) {
    int idx = base + j;
    if (idx < NN) {
      int v = texcl + loc[j];
      row_start[idx] = v;
      cursor[idx] = v;
    }
  }
}

__global__ void k_dinv(const int* __restrict__ cnt, float* __restrict__ dinv) {
  int i = blockIdx.x * 256 + threadIdx.x;
  if (i < NN) dinv[i] = rsqrtf((float)cnt[i] + 1.0f);
}

__global__ void k_fill(const int* __restrict__ src, const int* __restrict__ dst,
                       int* __restrict__ cursor, int* __restrict__ col) {
  int e = blockIdx.x * 256 + threadIdx.x;
  if (e < NE) {
    int d = dst[e];
    int pos = atomicAdd(&cursor[d], 1);
    col[pos] = src[e];
  }
}

// ---------------- dense matmul: X[nrows,K] @ W[K,OUT] -> T[nrows,OUT] ----------------
// lane=row. X staged to LDS transposed in k-chunks of 32: xs[k][row], row-stride 257
// (odd -> conflict-free scalar reads/writes). Per k: 1 ds_read_b32 feeds OUT FMAs
// whose W operand is wave-uniform (s_load from scalar cache).
template <int K, int OUT>
__global__ void k_mm3(const float* __restrict__ X, const float* __restrict__ W,
                      float* __restrict__ T, int nrows) {
  __shared__ float xs[32][257];
  int tid = threadIdx.x;
  int row = blockIdx.x * 256 + tid;
  float acc[OUT];
#pragma unroll
  for (int j = 0; j < OUT; j++) acc[j] = 0.f;

  for (int c = 0; c < K / 32; c++) {
    // stage 256 rows x 32 k-values, transposed into LDS
#pragma unroll
    for (int i = 0; i < 8; i++) {
      int f = i * 256 + tid;      // float4 index in tile
      int r = f >> 3, kq = f & 7;
      int gr = blockIdx.x * 256 + r;
      int grc = gr < nrows ? gr : nrows - 1;  // clamp tail loads
      float4 v = *(const float4*)(X + (size_t)grc * K + c * 32 + 4 * kq);
      xs[4 * kq + 0][r] = v.x;
      xs[4 * kq + 1][r] = v.y;
      xs[4 * kq + 2][r] = v.z;
      xs[4 * kq + 3][r] = v.w;
    }
    __syncthreads();
    const float* Wc = W + c * 32 * OUT;
#pragma unroll 4
    for (int k = 0; k < 32; k++) {
      float x = xs[k][tid];
      const float* Wk = Wc + k * OUT;  // wave-uniform -> scalar loads
#pragma unroll
      for (int j = 0; j < OUT; j++) acc[j] = fmaf(x, Wk[j], acc[j]);
    }
    __syncthreads();
  }

  if (row < nrows) {
    if (OUT == 64) {
#pragma unroll
      for (int q = 0; q < 16; q++) {
        float4 o = {acc[4 * q + 0], acc[4 * q + 1], acc[4 * q + 2], acc[4 * q + 3]};
        ((float4*)(T + (size_t)row * 64))[q] = o;
      }
    } else {
#pragma unroll
      for (int j = 0; j < OUT; j++) T[(size_t)row * OUT + j] = acc[j];
    }
  }
}

// ---------------- aggregation (HID=64): one wave per node, 4 edges in flight ----------------
__global__ void k_agg64(const float* __restrict__ T, const int* __restrict__ row_start,
                        const int* __restrict__ cnt, const int* __restrict__ col,
                        const float* __restrict__ dinv, const float* __restrict__ bias,
                        float* __restrict__ G, int relu) {
  int lane = threadIdx.x & 63;
  int wv = threadIdx.x >> 6;
  int node = blockIdx.x * 4 + wv;
  if (node >= NN) return;
  int grp = lane >> 4;  // which of 4 concurrent edges
  int q = lane & 15;    // float4 slot
  int s = row_start[node];
  int c = cnt[node];
  float4 acc = {0.f, 0.f, 0.f, 0.f};
  for (int i = 0; i < c; i += 4) {
    int j = i + grp;
    if (j < c) {
      int src = col[s + j];
      float dv = dinv[src];
      float4 t = ((const float4*)(T + (size_t)src * 64))[q];
      acc.x += t.x * dv;
      acc.y += t.y * dv;
      acc.z += t.z * dv;
      acc.w += t.w * dv;
    }
  }
  acc.x += __shfl_xor(acc.x, 16, 64);
  acc.y += __shfl_xor(acc.y, 16, 64);
  acc.z += __shfl_xor(acc.z, 16, 64);
  acc.w += __shfl_xor(acc.w, 16, 64);
  acc.x += __shfl_xor(acc.x, 32, 64);
  acc.y += __shfl_xor(acc.y, 32, 64);
  acc.z += __shfl_xor(acc.z, 32, 64);
  acc.w += __shfl_xor(acc.w, 32, 64);
  if (grp == 0) {
    float di = dinv[node];
    float dd = di * di;
    float4 ts = ((const float4*)(T + (size_t)node * 64))[q];
    float4 bs = ((const float4*)bias)[q];
    float4 o;
    o.x = acc.x * di + ts.x * dd + bs.x;
    o.y = acc.y * di + ts.y * dd + bs.y;
    o.z = acc.z * di + ts.z * dd + bs.z;
    o.w = acc.w * di + ts.w * dd + bs.w;
    if (relu) {
      o.x = fmaxf(o.x, 0.f);
      o.y = fmaxf(o.y, 0.f);
      o.z = fmaxf(o.z, 0.f);
      o.w = fmaxf(o.w, 0.f);
    }
    ((float4*)(G + (size_t)node * 64))[q] = o;
  }
}

// ---------------- BN stats: per-feature sum & sumsq -> fp64 accumulators ----------------
__global__ void k_stats(const float* __restrict__ H, double* __restrict__ st) {
  int f = threadIdx.x & 63;
  int g = threadIdx.x >> 6;
  float s1 = 0.f, s2 = 0.f;
  for (int r = blockIdx.x * 4 + g; r < NN; r += gridDim.x * 4) {
    float v = H[(size_t)r * 64 + f];
    s1 += v;
    s2 += v * v;
  }
  __shared__ float a[256], b[256];
  a[threadIdx.x] = s1;
  b[threadIdx.x] = s2;
  __syncthreads();
  if (threadIdx.x < 64) {
    float t1 = a[f] + a[f + 64] + a[f + 128] + a[f + 192];
    float t2 = b[f] + b[f + 64] + b[f + 128] + b[f + 192];
    unsafeAtomicAdd(&st[f], (double)t1);
    unsafeAtomicAdd(&st[64 + f], (double)t2);
  }
}

__global__ void k_bnscale(const double* __restrict__ st, const float* __restrict__ gamma,
                          const float* __restrict__ beta, float* __restrict__ sc) {
  int f = threadIdx.x;
  if (f < 64) {
    double m = st[f] / (double)NN;
    double var = st[64 + f] / (double)NN - m * m;
    float scale = gamma[f] * rsqrtf((float)var + EPSF);
    sc[f] = scale;
    sc[64 + f] = beta[f] - (float)m * scale;
  }
}

// ---------------- BN apply (+ optional residual), float4 over [N,64] ----------------
__global__ void k_bnapply(const float* __restrict__ G, const float* __restrict__ sc,
                          const float* __restrict__ res, float* __restrict__ Hout) {
  int i = blockIdx.x * 256 + threadIdx.x;
  if (i >= NN * 16) return;
  float4 v = ((const float4*)G)[i];
  int q = i & 15;
  float4 s = ((const float4*)sc)[q];
  float4 sh = ((const float4*)(sc + 64))[q];
  float4 o;
  o.x = v.x * s.x + sh.x;
  o.y = v.y * s.y + sh.y;
  o.z = v.z * s.z + sh.z;
  o.w = v.w * s.w + sh.w;
  if (res != nullptr) {
    float4 r = ((const float4*)res)[i];
    o.x += r.x; o.y += r.y; o.z += r.z; o.w += r.w;
  }
  ((float4*)Hout)[i] = o;
}

// ---------------- final aggregation (dim 2) ----------------
__global__ void k_agg2(const float* __restrict__ T2, const int* __restrict__ row_start,
                       const int* __restrict__ cnt, const int* __restrict__ col,
                       const float* __restrict__ dinv, const float* __restrict__ bias,
                       float* __restrict__ G2) {
  int idx = blockIdx.x * 256 + threadIdx.x;
  if (idx >= NN * 2) return;
  int node = idx >> 1, f = idx & 1;
  int s = row_start[node];
  int c = cnt[node];
  float acc = 0.f;
  for (int i = 0; i < c; i++) {
    int src = col[s + i];
    acc += T2[(size_t)src * 2 + f] * dinv[src];
  }
  float di = dinv[node];
  G2[idx] = acc * di + T2[idx] * di * di + bias[f];
}

// ---------------- segment mean pool ----------------
__global__ void k_pool(const float* __restrict__ G2, const int* __restrict__ batch,
                       float* __restrict__ pool, int* __restrict__ pcnt) {
  __shared__ float pl[128];
  __shared__ int pc[64];
  int tid = threadIdx.x;
  if (tid < 128) pl[tid] = 0.f;
  if (tid < 64) pc[tid] = 0;
  __syncthreads();
  int node = blockIdx.x * 128 + (tid >> 1);
  int f = tid & 1;
  if (node < NN) {
    int b = batch[node];
    atomicAdd(&pl[b * 2 + f], G2[(size_t)node * 2 + f]);
    if (f == 0) atomicAdd(&pc[b], 1);
  }
  __syncthreads();
  if (tid < 128 && pl[tid] != 0.f) unsafeAtomicAdd(&pool[tid], pl[tid]);
  if (tid < 64 && pc[tid] != 0) atomicAdd(&pcnt[tid], pc[tid]);
}

__global__ void k_div(const float* __restrict__ pool, const int* __restrict__ pcnt,
                      float* __restrict__ out) {
  int i = threadIdx.x;
  if (i < 128) {
    int c = pcnt[i >> 1];
    out[i] = pool[i] / (float)(c > 0 ? c : 1);
  }
}

extern "C" void kernel_launch(void* const* d_in, const int* in_sizes, int n_in,
                              void* d_out, int out_size, void* d_ws, size_t ws_size,
                              hipStream_t stream) {
  (void)in_sizes; (void)n_in; (void)out_size; (void)ws_size;
  const float* x     = (const float*)d_in[0];
  const float* W_in  = (const float*)d_in[1];
  const float* b_in  = (const float*)d_in[2];
  const float* W_h   = (const float*)d_in[3];
  const float* b_h   = (const float*)d_in[4];
  const float* W_out = (const float*)d_in[5];
  const float* b_out = (const float*)d_in[6];
  const float* gamma = (const float*)d_in[7];
  const float* beta  = (const float*)d_in[8];
  const int*   ei    = (const int*)d_in[9];
  const int*   batch = (const int*)d_in[10];
  const int* src = ei;
  const int* dst = ei + NE;
  float* out = (float*)d_out;

  char* w = (char*)d_ws;
  size_t off = 0;
  auto alloc = [&](size_t bytes) -> void* {
    void* p = (void*)(w + off);
    off += (bytes + 511) & ~(size_t)511;
    return p;
  };
  int*    deg   = (int*)alloc((size_t)NN * 4);
  int*    rowp  = (int*)alloc((size_t)NN * 4);
  int*    cur   = (int*)alloc((size_t)NN * 4);
  int*    col   = (int*)alloc((size_t)NE * 4);
  float*  dinv  = (float*)alloc((size_t)NN * 4);
  int*    bsum  = (int*)alloc(512);
  char*   zzone = (char*)alloc(3840);
  double* stats = (double*)zzone;
  float*  pool  = (float*)(zzone + 3072);
  int*    pcnt  = (int*)(zzone + 3072 + 512);
  float*  bnsc  = (float*)alloc(512);
  float*  buf0  = (float*)alloc((size_t)NN * HID * 4);
  float*  buf1  = (float*)alloc((size_t)NN * HID * 4);
  float*  buf2  = (float*)alloc((size_t)NN * HID * 4);
  float*  T2    = (float*)alloc((size_t)NN * 2 * 4);
  float*  G2    = (float*)alloc((size_t)NN * 2 * 4);

  hipMemsetAsync(deg, 0, (size_t)NN * 4, stream);
  hipMemsetAsync(zzone, 0, 3840, stream);

  // graph prep
  k_count<<<(NE + 255) / 256, 256, 0, stream>>>(dst, deg);
  k_scan_partial<<<98, 256, 0, stream>>>(deg, bsum);
  k_scan_serial<<<1, 64, 0, stream>>>(bsum, 98);
  k_scan_apply<<<98, 256, 0, stream>>>(deg, bsum, rowp, cur);
  k_dinv<<<(NN + 255) / 256, 256, 0, stream>>>(deg, dinv);
  k_fill<<<(NE + 255) / 256, 256, 0, stream>>>(src, dst, cur, col);

  const int mmgrid = (NN + 255) / 256;  // 391

  // layer 1: x(128) -> buf2(64)
  k_mm3<IND, HID><<<mmgrid, 256, 0, stream>>>(x, W_in, buf0, NN);
  k_agg64<<<(NN + 3) / 4, 256, 0, stream>>>(buf0, rowp, deg, col, dinv, b_in, buf1, 1);
  k_stats<<<512, 256, 0, stream>>>(buf1, stats);
  k_bnscale<<<1, 64, 0, stream>>>(stats, gamma, beta, bnsc);
  k_bnapply<<<6250, 256, 0, stream>>>(buf1, bnsc, nullptr, buf2);

  // layer 2: buf2 -> buf0 (res buf2)
  k_mm3<HID, HID><<<mmgrid, 256, 0, stream>>>(buf2, W_h, buf0, NN);
  k_agg64<<<(NN + 3) / 4, 256, 0, stream>>>(buf0, rowp, deg, col, dinv, b_h, buf1, 1);
  k_stats<<<512, 256, 0, stream>>>(buf1, stats + 128);
  k_bnscale<<<1, 64, 0, stream>>>(stats + 128, gamma + 64, beta + 64, bnsc);
  k_bnapply<<<6250, 256, 0, stream>>>(buf1, bnsc, buf2, buf0);

  // layer 3: buf0 -> buf1 (res buf0)
  k_mm3<HID, HID><<<mmgrid, 256, 0, stream>>>(buf0, W_h + HID * HID, buf1, NN);
  k_agg64<<<(NN + 3) / 4, 256, 0, stream>>>(buf1, rowp, deg, col, dinv, b_h + HID, buf2, 1);
  k_stats<<<512, 256, 0, stream>>>(buf2, stats + 256);
  k_bnscale<<<1, 64, 0, stream>>>(stats + 256, gamma + 128, beta + 128, bnsc);
  k_bnapply<<<6250, 256, 0, stream>>>(buf2, bnsc, buf0, buf1);

  // output layer: buf1 -> out
  k_mm3<HID, 2><<<mmgrid, 256, 0, stream>>>(buf1, W_out, T2, NN);
  k_agg2<<<(2 * NN + 255) / 256, 256, 0, stream>>>(T2, rowp, deg, col, dinv, b_out, G2);
  k_pool<<<(NN + 127) / 128, 256, 0, stream>>>(G2, batch, pool, pcnt);
  k_div<<<1, 128, 0, stream>>>(pool, pcnt, out);
}

// Round 4
// 644.864 us; speedup vs baseline: 2.8853x; 1.1364x over previous
//
#include <hip/hip_runtime.h>

// EnhancedGNN on MI355X.
// Pipeline: CSR build -> [mm -> gather-agg(+bias,relu) -> BN stats -> BN apply(+res)] x3
//           -> fused(BN3 + mm 64->2) -> gather-agg -> segment mean pool.
// R3: mm rewritten with register blocking (4 rows x 16 outs / thread), W + X both in
//     LDS. Scalar-operand designs (R1/R2) were latency-bound: SGPR cap ~102/wave
//     forces s_load inside the k-loop, serializing on shared lgkmcnt (VALUBusy 2.6%).
//     Per k: 4 ds_read_b128 (W) + 4 ds_read_b32 (X) -> 64 FMA (VALU-bound).

#define NN 100000
#define NE 1200000
#define NBATCH 64
#define IND 128
#define HID 64
#define EPSF 1e-5f

// ---------------- graph prep ----------------
__global__ void k_count(const int* __restrict__ dst, int* __restrict__ cnt) {
  int e = blockIdx.x * 256 + threadIdx.x;
  if (e < NE) atomicAdd(&cnt[dst[e]], 1);
}

__global__ void k_scan_partial(const int* __restrict__ cnt, int* __restrict__ bsum) {
  __shared__ int red[256];
  int base = blockIdx.x * 1024;
  int s = 0;
  for (int i = threadIdx.x; i < 1024; i += 256) {
    int idx = base + i;
    if (idx < NN) s += cnt[idx];
  }
  red[threadIdx.x] = s;
  __syncthreads();
  for (int off = 128; off > 0; off >>= 1) {
    if (threadIdx.x < off) red[threadIdx.x] += red[threadIdx.x + off];
    __syncthreads();
  }
  if (threadIdx.x == 0) bsum[blockIdx.x] = red[0];
}

__global__ void k_scan_serial(int* __restrict__ bsum, int nb) {
  if (threadIdx.x == 0 && blockIdx.x == 0) {
    int acc = 0;
    for (int i = 0; i < nb; i++) { int v = bsum[i]; bsum[i] = acc; acc += v; }
  }
}

__global__ void k_scan_apply(const int* __restrict__ cnt, const int* __restrict__ bsum,
                             int* __restrict__ row_start, int* __restrict__ cursor) {
  __shared__ int a[256];
  int tid = threadIdx.x;
  int base = blockIdx.x * 1024 + tid * 4;
  int loc[4];
  int tsum = 0;
  for (int j = 0; j < 4; j++) {
    int idx = base + j;
    int v = (idx < NN) ? cnt[idx] : 0;
    loc[j] = tsum;
    tsum += v;
  }
  a[tid] = tsum;
  __syncthreads();
  for (int off = 1; off < 256; off <<= 1) {
    int v = (tid >= off) ? a[tid - off] : 0;
    __syncthreads();
    a[tid] += v;
    __syncthreads();
  }
  int texcl = a[tid] - tsum + bsum[blockIdx.x];
  for (int j = 0; j < 4; j++) {
    int idx = base + j;
    if (idx < NN) {
      int v = texcl + loc[j];
      row_start[idx] = v;
      cursor[idx] = v;
    }
  }
}

__global__ void k_dinv(const int* __restrict__ cnt, float* __restrict__ dinv) {
  int i = blockIdx.x * 256 + threadIdx.x;
  if (i < NN) dinv[i] = rsqrtf((float)cnt[i] + 1.0f);
}

__global__ void k_fill(const int* __restrict__ src, const int* __restrict__ dst,
                       int* __restrict__ cursor, int* __restrict__ col) {
  int e = blockIdx.x * 256 + threadIdx.x;
  if (e < NE) {
    int d = dst[e];
    int pos = atomicAdd(&cursor[d], 1);
    col[pos] = src[e];
  }
}

// ---------------- dense matmul: X[nrows,K] @ W[K,64] -> T[nrows,64] ----------------
// Register-blocked: thread t -> jq=t&3 (16 outputs), rg=t>>2 (rows rg+64m, m=0..3).
// acc as float4[4][4]. W fully in LDS; X transposed in LDS in 16-k chunks.
template <int K>
__global__ void k_mm4(const float* __restrict__ X, const float* __restrict__ W,
                      float* __restrict__ T, int nrows) {
  __shared__ float Wl[K * 64];
  __shared__ float xs[16][257];
  int tid = threadIdx.x;
  // stage W (coalesced float4)
#pragma unroll
  for (int i = 0; i < K / 16; i++) {
    int f = i * 256 + tid;
    ((float4*)Wl)[f] = ((const float4*)W)[f];
  }
  int jq = tid & 3;        // output quad group: cols 16*jq .. 16*jq+15
  int rg = tid >> 2;       // row group: rows rg, rg+64, rg+128, rg+192
  int rbase = blockIdx.x * 256;
  float4 acc[4][4];
#pragma unroll
  for (int m = 0; m < 4; m++)
#pragma unroll
    for (int q = 0; q < 4; q++) acc[m][q] = {0.f, 0.f, 0.f, 0.f};

  for (int c = 0; c < K / 16; c++) {
    // stage 256 rows x 16 k-values, transposed
#pragma unroll
    for (int i = 0; i < 4; i++) {
      int f = i * 256 + tid;          // float4 index in tile [0,1024)
      int r = f >> 2, kq = f & 3;     // r row, kq: k-quad
      int gr = rbase + r;
      int grc = gr < nrows ? gr : nrows - 1;
      float4 v = *(const float4*)(X + (size_t)grc * K + c * 16 + 4 * kq);
      xs[4 * kq + 0][r] = v.x;
      xs[4 * kq + 1][r] = v.y;
      xs[4 * kq + 2][r] = v.z;
      xs[4 * kq + 3][r] = v.w;
    }
    __syncthreads();
    const float* Wc = Wl + c * 16 * 64 + jq * 16;
#pragma unroll
    for (int kk = 0; kk < 16; kk++) {
      float4 w0 = *(const float4*)(Wc + kk * 64 + 0);
      float4 w1 = *(const float4*)(Wc + kk * 64 + 4);
      float4 w2 = *(const float4*)(Wc + kk * 64 + 8);
      float4 w3 = *(const float4*)(Wc + kk * 64 + 12);
      float x0 = xs[kk][rg];
      float x1 = xs[kk][rg + 64];
      float x2 = xs[kk][rg + 128];
      float x3 = xs[kk][rg + 192];
      float xm[4] = {x0, x1, x2, x3};
      float4 wq[4] = {w0, w1, w2, w3};
#pragma unroll
      for (int m = 0; m < 4; m++)
#pragma unroll
        for (int q = 0; q < 4; q++) {
          acc[m][q].x = fmaf(xm[m], wq[q].x, acc[m][q].x);
          acc[m][q].y = fmaf(xm[m], wq[q].y, acc[m][q].y);
          acc[m][q].z = fmaf(xm[m], wq[q].z, acc[m][q].z);
          acc[m][q].w = fmaf(xm[m], wq[q].w, acc[m][q].w);
        }
    }
    __syncthreads();
  }

#pragma unroll
  for (int m = 0; m < 4; m++) {
    int row = rbase + rg + 64 * m;
    if (row < nrows) {
#pragma unroll
      for (int q = 0; q < 4; q++)
        ((float4*)(T + (size_t)row * 64 + jq * 16))[q] = acc[m][q];
    }
  }
}

// ---------------- aggregation (HID=64): one wave per node, 4 edges in flight ----------------
__global__ void k_agg64(const float* __restrict__ T, const int* __restrict__ row_start,
                        const int* __restrict__ cnt, const int* __restrict__ col,
                        const float* __restrict__ dinv, const float* __restrict__ bias,
                        float* __restrict__ G, int relu) {
  int lane = threadIdx.x & 63;
  int wv = threadIdx.x >> 6;
  int node = blockIdx.x * 4 + wv;
  if (node >= NN) return;
  int grp = lane >> 4;
  int q = lane & 15;
  int s = row_start[node];
  int c = cnt[node];
  float4 acc = {0.f, 0.f, 0.f, 0.f};
  for (int i = 0; i < c; i += 4) {
    int j = i + grp;
    if (j < c) {
      int src = col[s + j];
      float dv = dinv[src];
      float4 t = ((const float4*)(T + (size_t)src * 64))[q];
      acc.x += t.x * dv;
      acc.y += t.y * dv;
      acc.z += t.z * dv;
      acc.w += t.w * dv;
    }
  }
  acc.x += __shfl_xor(acc.x, 16, 64);
  acc.y += __shfl_xor(acc.y, 16, 64);
  acc.z += __shfl_xor(acc.z, 16, 64);
  acc.w += __shfl_xor(acc.w, 16, 64);
  acc.x += __shfl_xor(acc.x, 32, 64);
  acc.y += __shfl_xor(acc.y, 32, 64);
  acc.z += __shfl_xor(acc.z, 32, 64);
  acc.w += __shfl_xor(acc.w, 32, 64);
  if (grp == 0) {
    float di = dinv[node];
    float dd = di * di;
    float4 ts = ((const float4*)(T + (size_t)node * 64))[q];
    float4 bs = ((const float4*)bias)[q];
    float4 o;
    o.x = acc.x * di + ts.x * dd + bs.x;
    o.y = acc.y * di + ts.y * dd + bs.y;
    o.z = acc.z * di + ts.z * dd + bs.z;
    o.w = acc.w * di + ts.w * dd + bs.w;
    if (relu) {
      o.x = fmaxf(o.x, 0.f);
      o.y = fmaxf(o.y, 0.f);
      o.z = fmaxf(o.z, 0.f);
      o.w = fmaxf(o.w, 0.f);
    }
    ((float4*)(G + (size_t)node * 64))[q] = o;
  }
}

// ---------------- BN stats ----------------
__global__ void k_stats(const float* __restrict__ H, double* __restrict__ st) {
  int f = threadIdx.x & 63;
  int g = threadIdx.x >> 6;
  float s1 = 0.f, s2 = 0.f;
  for (int r = blockIdx.x * 4 + g; r < NN; r += gridDim.x * 4) {
    float v = H[(size_t)r * 64 + f];
    s1 += v;
    s2 += v * v;
  }
  __shared__ float a[256], b[256];
  a[threadIdx.x] = s1;
  b[threadIdx.x] = s2;
  __syncthreads();
  if (threadIdx.x < 64) {
    float t1 = a[f] + a[f + 64] + a[f + 128] + a[f + 192];
    float t2 = b[f] + b[f + 64] + b[f + 128] + b[f + 192];
    unsafeAtomicAdd(&st[f], (double)t1);
    unsafeAtomicAdd(&st[64 + f], (double)t2);
  }
}

__global__ void k_bnscale(const double* __restrict__ st, const float* __restrict__ gamma,
                          const float* __restrict__ beta, float* __restrict__ sc) {
  int f = threadIdx.x;
  if (f < 64) {
    double m = st[f] / (double)NN;
    double var = st[64 + f] / (double)NN - m * m;
    float scale = gamma[f] * rsqrtf((float)var + EPSF);
    sc[f] = scale;
    sc[64 + f] = beta[f] - (float)m * scale;
  }
}

// ---------------- BN apply (+ optional residual) ----------------
__global__ void k_bnapply(const float* __restrict__ G, const float* __restrict__ sc,
                          const float* __restrict__ res, float* __restrict__ Hout) {
  int i = blockIdx.x * 256 + threadIdx.x;
  if (i >= NN * 16) return;
  float4 v = ((const float4*)G)[i];
  int q = i & 15;
  float4 s = ((const float4*)sc)[q];
  float4 sh = ((const float4*)(sc + 64))[q];
  float4 o;
  o.x = v.x * s.x + sh.x;
  o.y = v.y * s.y + sh.y;
  o.z = v.z * s.z + sh.z;
  o.w = v.w * s.w + sh.w;
  if (res != nullptr) {
    float4 r = ((const float4*)res)[i];
    o.x += r.x; o.y += r.y; o.z += r.z; o.w += r.w;
  }
  ((float4*)Hout)[i] = o;
}

// ---------------- fused: BN3 apply + residual + matmul 64->2 ----------------
__global__ void k_bnmmout(const float* __restrict__ G, const float* __restrict__ sc,
                          const float* __restrict__ res, const float* __restrict__ W,
                          float* __restrict__ T2, int nrows) {
  __shared__ float Wl[128];   // W[64][2]
  __shared__ float scl[128];  // scale | shift
  int tid = threadIdx.x;
  if (tid < 32) ((float4*)Wl)[tid] = ((const float4*)W)[tid];
  else if (tid < 64) ((float4*)scl)[tid - 32] = ((const float4*)sc)[tid - 32];
  __syncthreads();
  int row = blockIdx.x * 256 + tid;
  if (row >= nrows) return;
  const float4* g4 = (const float4*)(G + (size_t)row * 64);
  const float4* r4 = (const float4*)(res + (size_t)row * 64);
  float a0 = 0.f, a1 = 0.f;
#pragma unroll
  for (int q = 0; q < 16; q++) {
    float4 v = g4[q];
    float4 rr = r4[q];
    float4 s = ((const float4*)scl)[q];
    float4 sh = ((const float4*)(scl + 64))[q];
    float h0 = v.x * s.x + sh.x + rr.x;
    float h1 = v.y * s.y + sh.y + rr.y;
    float h2 = v.z * s.z + sh.z + rr.z;
    float h3 = v.w * s.w + sh.w + rr.w;
    const float* wk = Wl + q * 8;  // 4 k-steps x 2 outs
    a0 = fmaf(h0, wk[0], a0); a1 = fmaf(h0, wk[1], a1);
    a0 = fmaf(h1, wk[2], a0); a1 = fmaf(h1, wk[3], a1);
    a0 = fmaf(h2, wk[4], a0); a1 = fmaf(h2, wk[5], a1);
    a0 = fmaf(h3, wk[6], a0); a1 = fmaf(h3, wk[7], a1);
  }
  T2[(size_t)row * 2 + 0] = a0;
  T2[(size_t)row * 2 + 1] = a1;
}

// ---------------- final aggregation (dim 2) ----------------
__global__ void k_agg2(const float* __restrict__ T2, const int* __restrict__ row_start,
                       const int* __restrict__ cnt, const int* __restrict__ col,
                       const float* __restrict__ dinv, const float* __restrict__ bias,
                       float* __restrict__ G2) {
  int idx = blockIdx.x * 256 + threadIdx.x;
  if (idx >= NN * 2) return;
  int node = idx >> 1, f = idx & 1;
  int s = row_start[node];
  int c = cnt[node];
  float acc = 0.f;
  for (int i = 0; i < c; i++) {
    int src = col[s + i];
    acc += T2[(size_t)src * 2 + f] * dinv[src];
  }
  float di = dinv[node];
  G2[idx] = acc * di + T2[idx] * di * di + bias[f];
}

// ---------------- segment mean pool ----------------
__global__ void k_pool(const float* __restrict__ G2, const int* __restrict__ batch,
                       float* __restrict__ pool, int* __restrict__ pcnt) {
  __shared__ float pl[128];
  __shared__ int pc[64];
  int tid = threadIdx.x;
  if (tid < 128) pl[tid] = 0.f;
  if (tid < 64) pc[tid] = 0;
  __syncthreads();
  int node = blockIdx.x * 128 + (tid >> 1);
  int f = tid & 1;
  if (node < NN) {
    int b = batch[node];
    atomicAdd(&pl[b * 2 + f], G2[(size_t)node * 2 + f]);
    if (f == 0) atomicAdd(&pc[b], 1);
  }
  __syncthreads();
  if (tid < 128 && pl[tid] != 0.f) unsafeAtomicAdd(&pool[tid], pl[tid]);
  if (tid < 64 && pc[tid] != 0) atomicAdd(&pcnt[tid], pc[tid]);
}

__global__ void k_div(const float* __restrict__ pool, const int* __restrict__ pcnt,
                      float* __restrict__ out) {
  int i = threadIdx.x;
  if (i < 128) {
    int c = pcnt[i >> 1];
    out[i] = pool[i] / (float)(c > 0 ? c : 1);
  }
}

extern "C" void kernel_launch(void* const* d_in, const int* in_sizes, int n_in,
                              void* d_out, int out_size, void* d_ws, size_t ws_size,
                              hipStream_t stream) {
  (void)in_sizes; (void)n_in; (void)out_size; (void)ws_size;
  const float* x     = (const float*)d_in[0];
  const float* W_in  = (const float*)d_in[1];
  const float* b_in  = (const float*)d_in[2];
  const float* W_h   = (const float*)d_in[3];
  const float* b_h   = (const float*)d_in[4];
  const float* W_out = (const float*)d_in[5];
  const float* b_out = (const float*)d_in[6];
  const float* gamma = (const float*)d_in[7];
  const float* beta  = (const float*)d_in[8];
  const int*   ei    = (const int*)d_in[9];
  const int*   batch = (const int*)d_in[10];
  const int* src = ei;
  const int* dst = ei + NE;
  float* out = (float*)d_out;

  char* w = (char*)d_ws;
  size_t off = 0;
  auto alloc = [&](size_t bytes) -> void* {
    void* p = (void*)(w + off);
    off += (bytes + 511) & ~(size_t)511;
    return p;
  };
  int*    deg   = (int*)alloc((size_t)NN * 4);
  int*    rowp  = (int*)alloc((size_t)NN * 4);
  int*    cur   = (int*)alloc((size_t)NN * 4);
  int*    col   = (int*)alloc((size_t)NE * 4);
  float*  dinv  = (float*)alloc((size_t)NN * 4);
  int*    bsum  = (int*)alloc(512);
  char*   zzone = (char*)alloc(3840);
  double* stats = (double*)zzone;
  float*  pool  = (float*)(zzone + 3072);
  int*    pcnt  = (int*)(zzone + 3072 + 512);
  float*  bnsc  = (float*)alloc(512);
  float*  buf0  = (float*)alloc((size_t)NN * HID * 4);
  float*  buf1  = (float*)alloc((size_t)NN * HID * 4);
  float*  buf2  = (float*)alloc((size_t)NN * HID * 4);
  float*  T2    = (float*)alloc((size_t)NN * 2 * 4);
  float*  G2    = (float*)alloc((size_t)NN * 2 * 4);

  hipMemsetAsync(deg, 0, (size_t)NN * 4, stream);
  hipMemsetAsync(zzone, 0, 3840, stream);

  // graph prep
  k_count<<<(NE + 255) / 256, 256, 0, stream>>>(dst, deg);
  k_scan_partial<<<98, 256, 0, stream>>>(deg, bsum);
  k_scan_serial<<<1, 64, 0, stream>>>(bsum, 98);
  k_scan_apply<<<98, 256, 0, stream>>>(deg, bsum, rowp, cur);
  k_dinv<<<(NN + 255) / 256, 256, 0, stream>>>(deg, dinv);
  k_fill<<<(NE + 255) / 256, 256, 0, stream>>>(src, dst, cur, col);

  const int mmgrid = (NN + 255) / 256;  // 391

  // layer 1: x(128) -> buf2(64)
  k_mm4<IND><<<mmgrid, 256, 0, stream>>>(x, W_in, buf0, NN);
  k_agg64<<<(NN + 3) / 4, 256, 0, stream>>>(buf0, rowp, deg, col, dinv, b_in, buf1, 1);
  k_stats<<<512, 256, 0, stream>>>(buf1, stats);
  k_bnscale<<<1, 64, 0, stream>>>(stats, gamma, beta, bnsc);
  k_bnapply<<<6250, 256, 0, stream>>>(buf1, bnsc, nullptr, buf2);

  // layer 2: buf2 -> buf0 (res buf2)
  k_mm4<HID><<<mmgrid, 256, 0, stream>>>(buf2, W_h, buf0, NN);
  k_agg64<<<(NN + 3) / 4, 256, 0, stream>>>(buf0, rowp, deg, col, dinv, b_h, buf1, 1);
  k_stats<<<512, 256, 0, stream>>>(buf1, stats + 128);
  k_bnscale<<<1, 64, 0, stream>>>(stats + 128, gamma + 64, beta + 64, bnsc);
  k_bnapply<<<6250, 256, 0, stream>>>(buf1, bnsc, buf2, buf0);

  // layer 3: buf0 -> buf2 (res buf0); BN3 fused into output mm
  k_mm4<HID><<<mmgrid, 256, 0, stream>>>(buf0, W_h + HID * HID, buf1, NN);
  k_agg64<<<(NN + 3) / 4, 256, 0, stream>>>(buf1, rowp, deg, col, dinv, b_h + HID, buf2, 1);
  k_stats<<<512, 256, 0, stream>>>(buf2, stats + 256);
  k_bnscale<<<1, 64, 0, stream>>>(stats + 256, gamma + 128, beta + 128, bnsc);

  // output layer: fused BN3+res+mm -> T2, then agg + pool
  k_bnmmout<<<mmgrid, 256, 0, stream>>>(buf2, bnsc, buf0, W_out, T2, NN);
  k_agg2<<<(2 * NN + 255) / 256, 256, 0, stream>>>(T2, rowp, deg, col, dinv, b_out, G2);
  k_pool<<<(NN + 127) / 128, 256, 0, stream>>>(G2, batch, pool, pcnt);
  k_div<<<1, 128, 0, stream>>>(pool, pcnt, out);
}

// Round 5
// 591.224 us; speedup vs baseline: 3.1471x; 1.0907x over previous
//
#include <hip/hip_runtime.h>

// EnhancedGNN on MI355X.
// R4: bucket-radix CSR build replaces count/scan/fill (k_fill was 90us with 83MB
//     write-allocate from random 4B scatters; bucketed scatter writes 8B pairs to
//     782 L2-resident streams, then per-bucket blocks build deg/rowp/dinv/col with
//     LDS atomics only). BN-apply fused into mm staging (k_mm4f, side-writes h for
//     the residual). agg2+pool fused. 19 launches.

#define NN 100000
#define NE 1200000
#define NBATCH 64
#define IND 128
#define HID 64
#define EPSF 1e-5f
#define NBUCK 782   // ceil(100000/128)
#define NPB 128     // nodes per bucket; bucket(d) = d >> 7

// ---------------- graph prep: bucket histogram ----------------
__global__ void k_ehist(const int* __restrict__ dst, int* __restrict__ gbh) {
  __shared__ int lh[NBUCK];
  int tid = threadIdx.x;
  for (int i = tid; i < NBUCK; i += 256) lh[i] = 0;
  __syncthreads();
  int base = blockIdx.x * 4096;
#pragma unroll
  for (int j = 0; j < 16; j++) {
    int e = base + j * 256 + tid;
    if (e < NE) atomicAdd(&lh[dst[e] >> 7], 1);
  }
  __syncthreads();
  for (int i = tid; i < NBUCK; i += 256) {
    int v = lh[i];
    if (v) atomicAdd(&gbh[i], v);
  }
}

// exclusive scan of 782 bucket counts -> bbase[0..NBUCK], bcur=bbase
__global__ void k_escan(const int* __restrict__ gbh, int* __restrict__ bbase,
                        int* __restrict__ bcur) {
  __shared__ int a[256];
  int tid = threadIdx.x;
  int loc[4];
  int tsum = 0;
  for (int j = 0; j < 4; j++) {
    int idx = tid * 4 + j;
    int v = (idx < NBUCK) ? gbh[idx] : 0;
    loc[j] = tsum;
    tsum += v;
  }
  a[tid] = tsum;
  __syncthreads();
  for (int off = 1; off < 256; off <<= 1) {
    int v = (tid >= off) ? a[tid - off] : 0;
    __syncthreads();
    a[tid] += v;
    __syncthreads();
  }
  int excl = a[tid] - tsum;
  for (int j = 0; j < 4; j++) {
    int idx = tid * 4 + j;
    if (idx < NBUCK) {
      int v = excl + loc[j];
      bbase[idx] = v;
      bcur[idx] = v;
    }
  }
  if (tid == 255) bbase[NBUCK] = a[255];
}

// scatter (src,dst) pairs into bucket-contiguous ebuf; LDS-aggregated cursor grabs
__global__ void k_escatter(const int* __restrict__ src, const int* __restrict__ dst,
                           int* __restrict__ bcur, unsigned long long* __restrict__ ebuf) {
  __shared__ int lh[NBUCK];
  __shared__ int lbase[NBUCK];
  int tid = threadIdx.x;
  for (int i = tid; i < NBUCK; i += 256) lh[i] = 0;
  __syncthreads();
  int base = blockIdx.x * 4096;
  int sv[16], dv[16], rk[16];
#pragma unroll
  for (int j = 0; j < 16; j++) {
    int e = base + j * 256 + tid;
    if (e < NE) {
      sv[j] = src[e];
      dv[j] = dst[e];
      rk[j] = atomicAdd(&lh[dv[j] >> 7], 1);
    } else {
      dv[j] = -1;
    }
  }
  __syncthreads();
  for (int i = tid; i < NBUCK; i += 256) {
    int v = lh[i];
    lbase[i] = v ? atomicAdd(&bcur[i], v) : 0;
  }
  __syncthreads();
#pragma unroll
  for (int j = 0; j < 16; j++) {
    if (dv[j] >= 0) {
      int b = dv[j] >> 7;
      ebuf[lbase[b] + rk[j]] =
          (unsigned long long)(unsigned)sv[j] | ((unsigned long long)(unsigned)dv[j] << 32);
    }
  }
}

// one block per bucket: local hist -> deg/dinv, local scan -> rowp, LDS-cursor fill -> col
__global__ void k_bucket_csr(const unsigned long long* __restrict__ ebuf,
                             const int* __restrict__ bbase, int* __restrict__ deg,
                             int* __restrict__ rowp, float* __restrict__ dinv,
                             int* __restrict__ col) {
  __shared__ int ldeg[NPB];
  __shared__ int lcur[NPB];
  __shared__ int sred[NPB];
  int b = blockIdx.x, tid = threadIdx.x;
  int nbase = b * NPB;
  int e0 = bbase[b], e1 = bbase[b + 1];
  if (tid < NPB) ldeg[tid] = 0;
  __syncthreads();
  for (int e = e0 + tid; e < e1; e += 256) {
    int d = (int)(ebuf[e] >> 32) - nbase;
    atomicAdd(&ldeg[d], 1);
  }
  __syncthreads();
  if (tid < NPB) sred[tid] = ldeg[tid];
  __syncthreads();
  for (int off = 1; off < NPB; off <<= 1) {
    int v = 0;
    if (tid < NPB && tid >= off) v = sred[tid - off];
    __syncthreads();
    if (tid < NPB) sred[tid] += v;
    __syncthreads();
  }
  if (tid < NPB) {
    int excl = sred[tid] - ldeg[tid];
    lcur[tid] = excl;
    int gn = nbase + tid;
    if (gn < NN) {
      int dg = ldeg[tid];
      deg[gn] = dg;
      rowp[gn] = e0 + excl;
      dinv[gn] = rsqrtf((float)dg + 1.0f);
    }
  }
  __syncthreads();
  for (int e = e0 + tid; e < e1; e += 256) {
    unsigned long long p = ebuf[e];
    int s = (int)(unsigned)p;
    int d = (int)(p >> 32) - nbase;
    int r = atomicAdd(&lcur[d], 1);
    col[e0 + r] = s;
  }
}

// ---------------- dense matmul: X[nrows,K] @ W[K,64] -> T[nrows,64] ----------------
template <int K>
__global__ void k_mm4(const float* __restrict__ X, const float* __restrict__ W,
                      float* __restrict__ T, int nrows) {
  __shared__ float Wl[K * 64];
  __shared__ float xs[16][257];
  int tid = threadIdx.x;
#pragma unroll
  for (int i = 0; i < K / 16; i++) {
    int f = i * 256 + tid;
    ((float4*)Wl)[f] = ((const float4*)W)[f];
  }
  int jq = tid & 3;
  int rg = tid >> 2;
  int rbase = blockIdx.x * 256;
  float4 acc[4][4];
#pragma unroll
  for (int m = 0; m < 4; m++)
#pragma unroll
    for (int q = 0; q < 4; q++) acc[m][q] = {0.f, 0.f, 0.f, 0.f};

  for (int c = 0; c < K / 16; c++) {
#pragma unroll
    for (int i = 0; i < 4; i++) {
      int f = i * 256 + tid;
      int r = f >> 2, kq = f & 3;
      int gr = rbase + r;
      int grc = gr < nrows ? gr : nrows - 1;
      float4 v = *(const float4*)(X + (size_t)grc * K + c * 16 + 4 * kq);
      xs[4 * kq + 0][r] = v.x;
      xs[4 * kq + 1][r] = v.y;
      xs[4 * kq + 2][r] = v.z;
      xs[4 * kq + 3][r] = v.w;
    }
    __syncthreads();
    const float* Wc = Wl + c * 16 * 64 + jq * 16;
#pragma unroll
    for (int kk = 0; kk < 16; kk++) {
      float4 wq[4];
      wq[0] = *(const float4*)(Wc + kk * 64 + 0);
      wq[1] = *(const float4*)(Wc + kk * 64 + 4);
      wq[2] = *(const float4*)(Wc + kk * 64 + 8);
      wq[3] = *(const float4*)(Wc + kk * 64 + 12);
      float xm[4];
      xm[0] = xs[kk][rg];
      xm[1] = xs[kk][rg + 64];
      xm[2] = xs[kk][rg + 128];
      xm[3] = xs[kk][rg + 192];
#pragma unroll
      for (int m = 0; m < 4; m++)
#pragma unroll
        for (int q = 0; q < 4; q++) {
          acc[m][q].x = fmaf(xm[m], wq[q].x, acc[m][q].x);
          acc[m][q].y = fmaf(xm[m], wq[q].y, acc[m][q].y);
          acc[m][q].z = fmaf(xm[m], wq[q].z, acc[m][q].z);
          acc[m][q].w = fmaf(xm[m], wq[q].w, acc[m][q].w);
        }
    }
    __syncthreads();
  }

#pragma unroll
  for (int m = 0; m < 4; m++) {
    int row = rbase + rg + 64 * m;
    if (row < nrows) {
#pragma unroll
      for (int q = 0; q < 4; q++)
        ((float4*)(T + (size_t)row * 64 + jq * 16))[q] = acc[m][q];
    }
  }
}

// fused: h = BN(G)(+res) applied during staging; h side-written to Hside; T = h @ W
__global__ void k_mm4f(const float* __restrict__ G, const float* __restrict__ sc,
                       const float* __restrict__ res, float* __restrict__ Hside,
                       const float* __restrict__ W, float* __restrict__ T, int nrows) {
  __shared__ float Wl[64 * 64];
  __shared__ float xs[16][257];
  __shared__ float scl[128];
  int tid = threadIdx.x;
#pragma unroll
  for (int i = 0; i < 4; i++) {
    int f = i * 256 + tid;
    ((float4*)Wl)[f] = ((const float4*)W)[f];
  }
  if (tid < 32) ((float4*)scl)[tid] = ((const float4*)sc)[tid];
  __syncthreads();  // scl read during staging below
  int jq = tid & 3;
  int rg = tid >> 2;
  int rbase = blockIdx.x * 256;
  float4 acc[4][4];
#pragma unroll
  for (int m = 0; m < 4; m++)
#pragma unroll
    for (int q = 0; q < 4; q++) acc[m][q] = {0.f, 0.f, 0.f, 0.f};

  for (int c = 0; c < 4; c++) {
#pragma unroll
    for (int i = 0; i < 4; i++) {
      int f = i * 256 + tid;
      int r = f >> 2, kq = f & 3;
      int gr = rbase + r;
      int grc = gr < nrows ? gr : nrows - 1;
      int kof = c * 16 + 4 * kq;
      float4 v = *(const float4*)(G + (size_t)grc * 64 + kof);
      float4 s = ((const float4*)scl)[kof >> 2];
      float4 sh = ((const float4*)(scl + 64))[kof >> 2];
      v.x = v.x * s.x + sh.x;
      v.y = v.y * s.y + sh.y;
      v.z = v.z * s.z + sh.z;
      v.w = v.w * s.w + sh.w;
      if (res != nullptr) {
        float4 rr = *(const float4*)(res + (size_t)grc * 64 + kof);
        v.x += rr.x; v.y += rr.y; v.z += rr.z; v.w += rr.w;
      }
      if (gr < nrows) *(float4*)(Hside + (size_t)gr * 64 + kof) = v;
      xs[4 * kq + 0][r] = v.x;
      xs[4 * kq + 1][r] = v.y;
      xs[4 * kq + 2][r] = v.z;
      xs[4 * kq + 3][r] = v.w;
    }
    __syncthreads();
    const float* Wc = Wl + c * 16 * 64 + jq * 16;
#pragma unroll
    for (int kk = 0; kk < 16; kk++) {
      float4 wq[4];
      wq[0] = *(const float4*)(Wc + kk * 64 + 0);
      wq[1] = *(const float4*)(Wc + kk * 64 + 4);
      wq[2] = *(const float4*)(Wc + kk * 64 + 8);
      wq[3] = *(const float4*)(Wc + kk * 64 + 12);
      float xm[4];
      xm[0] = xs[kk][rg];
      xm[1] = xs[kk][rg + 64];
      xm[2] = xs[kk][rg + 128];
      xm[3] = xs[kk][rg + 192];
#pragma unroll
      for (int m = 0; m < 4; m++)
#pragma unroll
        for (int q = 0; q < 4; q++) {
          acc[m][q].x = fmaf(xm[m], wq[q].x, acc[m][q].x);
          acc[m][q].y = fmaf(xm[m], wq[q].y, acc[m][q].y);
          acc[m][q].z = fmaf(xm[m], wq[q].z, acc[m][q].z);
          acc[m][q].w = fmaf(xm[m], wq[q].w, acc[m][q].w);
        }
    }
    __syncthreads();
  }

#pragma unroll
  for (int m = 0; m < 4; m++) {
    int row = rbase + rg + 64 * m;
    if (row < nrows) {
#pragma unroll
      for (int q = 0; q < 4; q++)
        ((float4*)(T + (size_t)row * 64 + jq * 16))[q] = acc[m][q];
    }
  }
}

// ---------------- aggregation (HID=64): one wave per node, 4 edges in flight ----------------
__global__ void k_agg64(const float* __restrict__ T, const int* __restrict__ row_start,
                        const int* __restrict__ cnt, const int* __restrict__ col,
                        const float* __restrict__ dinv, const float* __restrict__ bias,
                        float* __restrict__ G, int relu) {
  int lane = threadIdx.x & 63;
  int wv = threadIdx.x >> 6;
  int node = blockIdx.x * 4 + wv;
  if (node >= NN) return;
  int grp = lane >> 4;
  int q = lane & 15;
  int s = row_start[node];
  int c = cnt[node];
  float4 acc = {0.f, 0.f, 0.f, 0.f};
  for (int i = 0; i < c; i += 4) {
    int j = i + grp;
    if (j < c) {
      int src = col[s + j];
      float dv = dinv[src];
      float4 t = ((const float4*)(T + (size_t)src * 64))[q];
      acc.x += t.x * dv;
      acc.y += t.y * dv;
      acc.z += t.z * dv;
      acc.w += t.w * dv;
    }
  }
  acc.x += __shfl_xor(acc.x, 16, 64);
  acc.y += __shfl_xor(acc.y, 16, 64);
  acc.z += __shfl_xor(acc.z, 16, 64);
  acc.w += __shfl_xor(acc.w, 16, 64);
  acc.x += __shfl_xor(acc.x, 32, 64);
  acc.y += __shfl_xor(acc.y, 32, 64);
  acc.z += __shfl_xor(acc.z, 32, 64);
  acc.w += __shfl_xor(acc.w, 32, 64);
  if (grp == 0) {
    float di = dinv[node];
    float dd = di * di;
    float4 ts = ((const float4*)(T + (size_t)node * 64))[q];
    float4 bs = ((const float4*)bias)[q];
    float4 o;
    o.x = acc.x * di + ts.x * dd + bs.x;
    o.y = acc.y * di + ts.y * dd + bs.y;
    o.z = acc.z * di + ts.z * dd + bs.z;
    o.w = acc.w * di + ts.w * dd + bs.w;
    if (relu) {
      o.x = fmaxf(o.x, 0.f);
      o.y = fmaxf(o.y, 0.f);
      o.z = fmaxf(o.z, 0.f);
      o.w = fmaxf(o.w, 0.f);
    }
    ((float4*)(G + (size_t)node * 64))[q] = o;
  }
}

// ---------------- BN stats ----------------
__global__ void k_stats(const float* __restrict__ H, double* __restrict__ st) {
  int f = threadIdx.x & 63;
  int g = threadIdx.x >> 6;
  float s1 = 0.f, s2 = 0.f;
  for (int r = blockIdx.x * 4 + g; r < NN; r += gridDim.x * 4) {
    float v = H[(size_t)r * 64 + f];
    s1 += v;
    s2 += v * v;
  }
  __shared__ float a[256], b[256];
  a[threadIdx.x] = s1;
  b[threadIdx.x] = s2;
  __syncthreads();
  if (threadIdx.x < 64) {
    float t1 = a[f] + a[f + 64] + a[f + 128] + a[f + 192];
    float t2 = b[f] + b[f + 64] + b[f + 128] + b[f + 192];
    unsafeAtomicAdd(&st[f], (double)t1);
    unsafeAtomicAdd(&st[64 + f], (double)t2);
  }
}

__global__ void k_bnscale(const double* __restrict__ st, const float* __restrict__ gamma,
                          const float* __restrict__ beta, float* __restrict__ sc) {
  int f = threadIdx.x;
  if (f < 64) {
    double m = st[f] / (double)NN;
    double var = st[64 + f] / (double)NN - m * m;
    float scale = gamma[f] * rsqrtf((float)var + EPSF);
    sc[f] = scale;
    sc[64 + f] = beta[f] - (float)m * scale;
  }
}

// ---------------- fused: BN3 apply + residual + matmul 64->2 ----------------
__global__ void k_bnmmout(const float* __restrict__ G, const float* __restrict__ sc,
                          const float* __restrict__ res, const float* __restrict__ W,
                          float* __restrict__ T2, int nrows) {
  __shared__ float Wl[128];
  __shared__ float scl[128];
  int tid = threadIdx.x;
  if (tid < 32) ((float4*)Wl)[tid] = ((const float4*)W)[tid];
  else if (tid < 64) ((float4*)scl)[tid - 32] = ((const float4*)sc)[tid - 32];
  __syncthreads();
  int row = blockIdx.x * 256 + tid;
  if (row >= nrows) return;
  const float4* g4 = (const float4*)(G + (size_t)row * 64);
  const float4* r4 = (const float4*)(res + (size_t)row * 64);
  float a0 = 0.f, a1 = 0.f;
#pragma unroll
  for (int q = 0; q < 16; q++) {
    float4 v = g4[q];
    float4 rr = r4[q];
    float4 s = ((const float4*)scl)[q];
    float4 sh = ((const float4*)(scl + 64))[q];
    float h0 = v.x * s.x + sh.x + rr.x;
    float h1 = v.y * s.y + sh.y + rr.y;
    float h2 = v.z * s.z + sh.z + rr.z;
    float h3 = v.w * s.w + sh.w + rr.w;
    const float* wk = Wl + q * 8;
    a0 = fmaf(h0, wk[0], a0); a1 = fmaf(h0, wk[1], a1);
    a0 = fmaf(h1, wk[2], a0); a1 = fmaf(h1, wk[3], a1);
    a0 = fmaf(h2, wk[4], a0); a1 = fmaf(h2, wk[5], a1);
    a0 = fmaf(h3, wk[6], a0); a1 = fmaf(h3, wk[7], a1);
  }
  T2[(size_t)row * 2 + 0] = a0;
  T2[(size_t)row * 2 + 1] = a1;
}

// ---------------- fused final aggregation (dim 2) + segment mean pool ----------------
__global__ void k_agg2pool(const float* __restrict__ T2, const int* __restrict__ rowp,
                           const int* __restrict__ cnt, const int* __restrict__ col,
                           const float* __restrict__ dinv, const float* __restrict__ bias,
                           const int* __restrict__ batch, float* __restrict__ pool,
                           int* __restrict__ pcnt) {
  __shared__ float pl[128];
  __shared__ int pc[64];
  int tid = threadIdx.x;
  if (tid < 128) pl[tid] = 0.f;
  if (tid < 64) pc[tid] = 0;
  __syncthreads();
  int idx = blockIdx.x * 256 + tid;
  if (idx < NN * 2) {
    int node = idx >> 1, f = idx & 1;
    int s = rowp[node];
    int c = cnt[node];
    float acc = 0.f;
    for (int i = 0; i < c; i++) {
      int sr = col[s + i];
      acc += T2[(size_t)sr * 2 + f] * dinv[sr];
    }
    float di = dinv[node];
    float v = acc * di + T2[idx] * di * di + bias[f];
    int bb = batch[node];
    atomicAdd(&pl[bb * 2 + f], v);
    if (f == 0) atomicAdd(&pc[bb], 1);
  }
  __syncthreads();
  if (tid < 128 && pl[tid] != 0.f) unsafeAtomicAdd(&pool[tid], pl[tid]);
  if (tid < 64 && pc[tid] != 0) atomicAdd(&pcnt[tid], pc[tid]);
}

__global__ void k_div(const float* __restrict__ pool, const int* __restrict__ pcnt,
                      float* __restrict__ out) {
  int i = threadIdx.x;
  if (i < 128) {
    int c = pcnt[i >> 1];
    out[i] = pool[i] / (float)(c > 0 ? c : 1);
  }
}

extern "C" void kernel_launch(void* const* d_in, const int* in_sizes, int n_in,
                              void* d_out, int out_size, void* d_ws, size_t ws_size,
                              hipStream_t stream) {
  (void)in_sizes; (void)n_in; (void)out_size; (void)ws_size;
  const float* x     = (const float*)d_in[0];
  const float* W_in  = (const float*)d_in[1];
  const float* b_in  = (const float*)d_in[2];
  const float* W_h   = (const float*)d_in[3];
  const float* b_h   = (const float*)d_in[4];
  const float* W_out = (const float*)d_in[5];
  const float* b_out = (const float*)d_in[6];
  const float* gamma = (const float*)d_in[7];
  const float* beta  = (const float*)d_in[8];
  const int*   ei    = (const int*)d_in[9];
  const int*   batch = (const int*)d_in[10];
  const int* src = ei;
  const int* dst = ei + NE;
  float* out = (float*)d_out;

  char* w = (char*)d_ws;
  size_t off = 0;
  auto alloc = [&](size_t bytes) -> void* {
    void* p = (void*)(w + off);
    off += (bytes + 511) & ~(size_t)511;
    return p;
  };
  int*    deg   = (int*)alloc((size_t)NN * 4);
  int*    rowp  = (int*)alloc((size_t)NN * 4);
  int*    col   = (int*)alloc((size_t)NE * 4);
  float*  dinv  = (float*)alloc((size_t)NN * 4);
  int*    bbase = (int*)alloc((NBUCK + 1) * 4);
  int*    bcur  = (int*)alloc(NBUCK * 4);
  // zeroed zone: stats (3*128 dbl = 3072) | pool (512) | pcnt (256) | gbh (782*4 = 3128)
  char*   zzone = (char*)alloc(7168);
  double* stats = (double*)zzone;
  float*  pool  = (float*)(zzone + 3072);
  int*    pcnt  = (int*)(zzone + 3072 + 512);
  int*    gbh   = (int*)(zzone + 3840);
  float*  bnsc  = (float*)alloc(3 * 512);
  float*  buf0  = (float*)alloc((size_t)NN * HID * 4);
  float*  buf1  = (float*)alloc((size_t)NN * HID * 4);
  float*  buf2  = (float*)alloc((size_t)NN * HID * 4);
  float*  T2    = (float*)alloc((size_t)NN * 2 * 4);
  // ebuf (9.6MB) aliases buf0: consumed by k_bucket_csr before buf0's first write
  unsigned long long* ebuf = (unsigned long long*)buf0;

  hipMemsetAsync(zzone, 0, 7040, stream);

  // graph prep: bucket-radix CSR build
  k_ehist<<<293, 256, 0, stream>>>(dst, gbh);
  k_escan<<<1, 256, 0, stream>>>(gbh, bbase, bcur);
  k_escatter<<<293, 256, 0, stream>>>(src, dst, bcur, ebuf);
  k_bucket_csr<<<NBUCK, 256, 0, stream>>>(ebuf, bbase, deg, rowp, dinv, col);

  const int mmgrid = (NN + 255) / 256;  // 391

  // layer 1: x(128) -> G1
  k_mm4<IND><<<mmgrid, 256, 0, stream>>>(x, W_in, buf0, NN);
  k_agg64<<<(NN + 3) / 4, 256, 0, stream>>>(buf0, rowp, deg, col, dinv, b_in, buf1, 1);
  k_stats<<<512, 256, 0, stream>>>(buf1, stats);
  k_bnscale<<<1, 64, 0, stream>>>(stats, gamma, beta, bnsc);

  // layer 2: h1 = BN1(G1) (side-> buf2); T2m = h1@W_h0 -> buf0
  k_mm4f<<<mmgrid, 256, 0, stream>>>(buf1, bnsc, nullptr, buf2, W_h, buf0, NN);
  k_agg64<<<(NN + 3) / 4, 256, 0, stream>>>(buf0, rowp, deg, col, dinv, b_h, buf1, 1);
  k_stats<<<512, 256, 0, stream>>>(buf1, stats + 128);
  k_bnscale<<<1, 64, 0, stream>>>(stats + 128, gamma + 64, beta + 64, bnsc + 128);

  // layer 3: h2 = BN2(G2)+h1 (side-> buf0); T3 = h2@W_h1 -> buf1 (T aliases G: per-block safe)
  k_mm4f<<<mmgrid, 256, 0, stream>>>(buf1, bnsc + 128, buf2, buf0, W_h + HID * HID, buf1, NN);
  k_agg64<<<(NN + 3) / 4, 256, 0, stream>>>(buf1, rowp, deg, col, dinv, b_h + HID, buf2, 1);
  k_stats<<<512, 256, 0, stream>>>(buf2, stats + 256);
  k_bnscale<<<1, 64, 0, stream>>>(stats + 256, gamma + 128, beta + 128, bnsc + 256);

  // output: h3 = BN3(G3)+h2 fused with mm 64->2, then agg+pool fused
  k_bnmmout<<<mmgrid, 256, 0, stream>>>(buf2, bnsc + 256, buf0, W_out, T2, NN);
  k_agg2pool<<<(2 * NN + 255) / 256, 256, 0, stream>>>(T2, rowp, deg, col, dinv, b_out,
                                                       batch, pool, pcnt);
  k_div<<<1, 128, 0, stream>>>(pool, pcnt, out);
}